// Round 1
// baseline (2249.869 us; speedup 1.0000x reference)
//
#include <hip/hip_runtime.h>
#include <stdint.h>

typedef unsigned short u16;
typedef unsigned int   u32;

// ---- bf16 helpers (hand-rolled, RNE) ----
__device__ __forceinline__ float bf2f(u16 u) {
    union { u32 i; float f; } t; t.i = ((u32)u) << 16; return t.f;
}
__device__ __forceinline__ u16 f2bf(float f) {
    union { u32 i; float f; } t; t.f = f;
    u32 b = t.i;
    u32 r = (b + 0x7fffu + ((b >> 16) & 1u)) >> 16;
    return (u16)r;
}

// Problem constants
// B=8, C=128, G=32 (4 ch/group), H=W=64, S=4096, scale=1/sqrt(128)
#define SCALE 0.08838834764831845f

// ============================================================
// Kernel 1: GroupNorm. One block per (b, g). 4 ch x 4096 = 16384
// contiguous floats per group. Output: bf16 hn [B][C][S].
// ============================================================
__global__ __launch_bounds__(256) void gn_kernel(
    const float* __restrict__ x, const float* __restrict__ gw,
    const float* __restrict__ gb, u16* __restrict__ hn)
{
    int b = blockIdx.x >> 5, g = blockIdx.x & 31;
    long base = ((long)(b * 128 + g * 4)) << 12;  // float index
    const float4* x4 = (const float4*)(x + base);

    float s = 0.f, ss = 0.f;
    for (int i = threadIdx.x; i < 4096; i += 256) {
        float4 v = x4[i];
        s  += v.x + v.y + v.z + v.w;
        ss += v.x * v.x + v.y * v.y + v.z * v.z + v.w * v.w;
    }
    #pragma unroll
    for (int off = 32; off > 0; off >>= 1) {
        s  += __shfl_xor(s,  off);
        ss += __shfl_xor(ss, off);
    }
    __shared__ float red[8];
    int wid = threadIdx.x >> 6;
    if ((threadIdx.x & 63) == 0) { red[wid * 2] = s; red[wid * 2 + 1] = ss; }
    __syncthreads();
    s  = red[0] + red[2] + red[4] + red[6];
    ss = red[1] + red[3] + red[5] + red[7];

    float mean = s * (1.f / 16384.f);
    float var  = ss * (1.f / 16384.f) - mean * mean;
    float rs   = rsqrtf(var + 1e-5f);

    ushort4* o4 = (ushort4*)(hn + base);
    for (int i = threadIdx.x; i < 4096; i += 256) {
        int c = g * 4 + (i >> 10);
        float gamma = gw[c] * rs;
        float beta  = gb[c] - mean * gamma;
        float4 v = x4[i];
        ushort4 o;
        o.x = f2bf(v.x * gamma + beta);
        o.y = f2bf(v.y * gamma + beta);
        o.z = f2bf(v.z * gamma + beta);
        o.w = f2bf(v.w * gamma + beta);
        o4[i] = o;
    }
}

// ============================================================
// Kernel 2: QKV projection. qkv[b][o][s] = sum_c w[o][c]*h[b][c][s] + bias[o]
// Block: (b, 64-s tile). h tile [128 c][64 s] staged fp32 in LDS
// (stored transposed [s][c] so the inner loop does float4 reads).
// Each thread: one s, 96 o values in blocks of 4.
// ============================================================
__global__ __launch_bounds__(256) void qkv_kernel(
    const u16* __restrict__ hn, const float* __restrict__ w,
    const float* __restrict__ bias, u16* __restrict__ qkv)
{
    __shared__ float h_lds[64][132];
    int b  = blockIdx.x >> 6;
    int s0 = (blockIdx.x & 63) << 6;
    int sl = threadIdx.x & 63, cg = threadIdx.x >> 6;

    const u16* hb = hn + ((long)b << 19);   // b*128*4096
    for (int c = cg; c < 128; c += 4)
        h_lds[sl][c] = bf2f(hb[(c << 12) + s0 + sl]);
    __syncthreads();

    const float4* w4 = (const float4*)w;
    u16* outb = qkv + (((long)b * 384) << 12);
    const float4* hrow = (const float4*)(&h_lds[sl][0]);
    int o0 = cg * 96;

    for (int g4 = 0; g4 < 24; ++g4) {
        int o = o0 + g4 * 4;
        float a0 = bias[o], a1 = bias[o + 1], a2 = bias[o + 2], a3 = bias[o + 3];
        #pragma unroll 4
        for (int c4 = 0; c4 < 32; ++c4) {
            float4 hv = hrow[c4];
            float4 w0 = w4[(o + 0) * 32 + c4];
            float4 w1 = w4[(o + 1) * 32 + c4];
            float4 w2 = w4[(o + 2) * 32 + c4];
            float4 w3 = w4[(o + 3) * 32 + c4];
            a0 += hv.x * w0.x + hv.y * w0.y + hv.z * w0.z + hv.w * w0.w;
            a1 += hv.x * w1.x + hv.y * w1.y + hv.z * w1.z + hv.w * w1.w;
            a2 += hv.x * w2.x + hv.y * w2.y + hv.z * w2.z + hv.w * w2.w;
            a3 += hv.x * w3.x + hv.y * w3.y + hv.z * w3.z + hv.w * w3.w;
        }
        outb[((o + 0) << 12) + s0 + sl] = f2bf(a0);
        outb[((o + 1) << 12) + s0 + sl] = f2bf(a1);
        outb[((o + 2) << 12) + s0 + sl] = f2bf(a2);
        outb[((o + 3) << 12) + s0 + sl] = f2bf(a3);
    }
}

// ============================================================
// Kernel 3: flash attention + final x*a multiply.
// Block: (b, 16 q-rows). 4 waves, each wave owns 4 q rows.
// Keys processed in 64-key tiles staged in LDS (packed bf16 pairs).
// Lane l owns key (l) for scores, channel pair (2l, 2l+1) for O.
// Online softmax (running m, l per row, replicated across lanes).
// ============================================================
__global__ __launch_bounds__(256) void attn_kernel(
    const u16* __restrict__ qkv, const float* __restrict__ x,
    float* __restrict__ out)
{
    __shared__ u32 k_lds[64][67];   // [c2][key]
    __shared__ u32 v_lds[64][67];   // [c2][key]
    __shared__ u32 q_lds[16][64];   // [row][c2]
    __shared__ float p_lds[4][4][64];

    int b  = blockIdx.x >> 8;
    int s0 = (blockIdx.x & 255) << 4;
    int tid = threadIdx.x, lane = tid & 63, wv = tid >> 6;

    const u16* Qg = qkv + (((long)b * 384) << 12);
    const u16* Kg = Qg + (128 << 12);
    const u16* Vg = Qg + (256 << 12);

    // stage Q tile [16 rows][64 c2]
    for (int i = tid; i < 1024; i += 256) {
        int c2 = i >> 4, r = i & 15;
        u32 lo = Qg[((2 * c2) << 12) + s0 + r];
        u32 hi = Qg[((2 * c2 + 1) << 12) + s0 + r];
        q_lds[r][c2] = lo | (hi << 16);
    }

    float mr[4] = {-1e30f, -1e30f, -1e30f, -1e30f};
    float lr[4] = {0.f, 0.f, 0.f, 0.f};
    float oa[4][2] = {{0.f,0.f},{0.f,0.f},{0.f,0.f},{0.f,0.f}};
    int wq = wv * 4;

    for (int kt = 0; kt < 64; ++kt) {
        int sk = kt << 6;
        __syncthreads();
        // stage K,V tile (also covers q_lds on first iteration)
        for (int c2 = wv; c2 < 64; c2 += 4) {
            int c = c2 * 2;
            u32 klo = Kg[(c << 12) + sk + lane];
            u32 khi = Kg[((c + 1) << 12) + sk + lane];
            k_lds[c2][lane] = klo | (khi << 16);
            u32 vlo = Vg[(c << 12) + sk + lane];
            u32 vhi = Vg[((c + 1) << 12) + sk + lane];
            v_lds[c2][lane] = vlo | (vhi << 16);
        }
        __syncthreads();

        // scores: sc[r] = dot(Q[wq+r], K[sk+lane])
        float sc[4] = {0.f, 0.f, 0.f, 0.f};
        #pragma unroll 4
        for (int c2 = 0; c2 < 64; ++c2) {
            u32 kv = k_lds[c2][lane];
            float k0 = bf2f((u16)kv), k1 = bf2f((u16)(kv >> 16));
            #pragma unroll
            for (int r = 0; r < 4; ++r) {
                u32 qv = q_lds[wq + r][c2];
                sc[r] += bf2f((u16)qv) * k0 + bf2f((u16)(qv >> 16)) * k1;
            }
        }

        // online softmax update
        #pragma unroll
        for (int r = 0; r < 4; ++r) {
            float scv = sc[r] * SCALE;
            float mt = scv;
            #pragma unroll
            for (int off = 32; off > 0; off >>= 1)
                mt = fmaxf(mt, __shfl_xor(mt, off));
            float mn = fmaxf(mr[r], mt);
            float alpha = __expf(mr[r] - mn);
            float p = __expf(scv - mn);
            float ps = p;
            #pragma unroll
            for (int off = 32; off > 0; off >>= 1)
                ps += __shfl_xor(ps, off);
            lr[r] = lr[r] * alpha + ps;
            mr[r] = mn;
            oa[r][0] *= alpha; oa[r][1] *= alpha;
            p_lds[wv][r][lane] = p;
        }

        // PV: oa[r][j] += sum_s p[r][s] * v[s][2*lane+j]
        #pragma unroll 4
        for (int s = 0; s < 64; ++s) {
            u32 vv = v_lds[lane][s];
            float v0 = bf2f((u16)vv), v1 = bf2f((u16)(vv >> 16));
            #pragma unroll
            for (int r = 0; r < 4; ++r) {
                float p = p_lds[wv][r][s];
                oa[r][0] += p * v0;
                oa[r][1] += p * v1;
            }
        }
    }

    // epilogue: normalize, transpose via LDS, out = x * a
    __syncthreads();
    float* o_lds = (float*)k_lds;   // 16*128 floats fits in k_lds
    #pragma unroll
    for (int r = 0; r < 4; ++r) {
        float inv = 1.f / lr[r];
        o_lds[(wq + r) * 128 + lane * 2 + 0] = oa[r][0] * inv;
        o_lds[(wq + r) * 128 + lane * 2 + 1] = oa[r][1] * inv;
    }
    __syncthreads();
    for (int i = tid; i < 2048; i += 256) {
        int c = i >> 4, r = i & 15;
        long gi = (((long)(b * 128 + c)) << 12) + s0 + r;
        out[gi] = x[gi] * o_lds[r * 128 + c];
    }
}

// ============================================================
extern "C" void kernel_launch(void* const* d_in, const int* in_sizes, int n_in,
                              void* d_out, int out_size, void* d_ws, size_t ws_size,
                              hipStream_t stream)
{
    const float* x    = (const float*)d_in[0];
    const float* gw   = (const float*)d_in[1];
    const float* gb   = (const float*)d_in[2];
    const float* w    = (const float*)d_in[3];
    const float* bias = (const float*)d_in[4];
    float* out = (float*)d_out;

    u16* hn  = (u16*)d_ws;                       // [8][128][4096] bf16 = 8 MB
    u16* qkv = hn + (size_t)8 * 128 * 4096;      // [8][384][4096] bf16 = 25 MB

    gn_kernel<<<256, 256, 0, stream>>>(x, gw, gb, hn);
    qkv_kernel<<<512, 256, 0, stream>>>(hn, w, bias, qkv);
    attn_kernel<<<2048, 256, 0, stream>>>(qkv, x, out);
}

// Round 2
// 343.462 us; speedup vs baseline: 6.5506x; 6.5506x over previous
//
#include <hip/hip_runtime.h>
#include <stdint.h>

typedef unsigned short u16;
typedef unsigned int   u32;
typedef __attribute__((ext_vector_type(8))) short bf16x8;
typedef __attribute__((ext_vector_type(4))) float f32x4;

#define SCALE 0.08838834764831845f

__device__ __forceinline__ float bf2f(u16 u) {
    union { u32 i; float f; } t; t.i = ((u32)u) << 16; return t.f;
}
__device__ __forceinline__ u16 f2bf(float f) {
    union { u32 i; float f; } t; t.f = f;
    u32 b = t.i;
    return (u16)((b + 0x7fffu + ((b >> 16) & 1u)) >> 16);
}

// async global->LDS, 16B per lane, linear LDS dest (wave-uniform base + lane*16)
__device__ __forceinline__ void gload16(const u16* g, u16* l) {
    __builtin_amdgcn_global_load_lds(
        (const __attribute__((address_space(1))) void*)g,
        (__attribute__((address_space(3))) void*)l, 16, 0, 0);
}

// ============================================================
// Kernel 1: GroupNorm. One block per (b, g). Output bf16 hn [B][C][S].
// ============================================================
__global__ __launch_bounds__(256) void gn_kernel(
    const float* __restrict__ x, const float* __restrict__ gw,
    const float* __restrict__ gb, u16* __restrict__ hn)
{
    int b = blockIdx.x >> 5, g = blockIdx.x & 31;
    long base = ((long)(b * 128 + g * 4)) << 12;
    const float4* x4 = (const float4*)(x + base);

    float s = 0.f, ss = 0.f;
    for (int i = threadIdx.x; i < 4096; i += 256) {
        float4 v = x4[i];
        s  += v.x + v.y + v.z + v.w;
        ss += v.x * v.x + v.y * v.y + v.z * v.z + v.w * v.w;
    }
    #pragma unroll
    for (int off = 32; off > 0; off >>= 1) {
        s  += __shfl_xor(s,  off);
        ss += __shfl_xor(ss, off);
    }
    __shared__ float red[8];
    int wid = threadIdx.x >> 6;
    if ((threadIdx.x & 63) == 0) { red[wid * 2] = s; red[wid * 2 + 1] = ss; }
    __syncthreads();
    s  = red[0] + red[2] + red[4] + red[6];
    ss = red[1] + red[3] + red[5] + red[7];

    float mean = s * (1.f / 16384.f);
    float var  = ss * (1.f / 16384.f) - mean * mean;
    float rs   = rsqrtf(var + 1e-5f);

    ushort4* o4 = (ushort4*)(hn + base);
    for (int i = threadIdx.x; i < 4096; i += 256) {
        int c = g * 4 + (i >> 10);
        float gamma = gw[c] * rs;
        float beta  = gb[c] - mean * gamma;
        float4 v = x4[i];
        ushort4 o;
        o.x = f2bf(v.x * gamma + beta);
        o.y = f2bf(v.y * gamma + beta);
        o.z = f2bf(v.z * gamma + beta);
        o.w = f2bf(v.w * gamma + beta);
        o4[i] = o;
    }
}

// ============================================================
// Kernel 2: QKV projection. Writes Q,K transposed [b][s][128] (for MFMA
// frag loads in attention) and V as [b][c][s].
// ============================================================
__global__ __launch_bounds__(256) void qkv_kernel(
    const u16* __restrict__ hn, const float* __restrict__ w,
    const float* __restrict__ bias,
    u16* __restrict__ Qt, u16* __restrict__ Kt, u16* __restrict__ Vv)
{
    __shared__ float h_lds[64][132];
    int b  = blockIdx.x >> 6;
    int s0 = (blockIdx.x & 63) << 6;
    int sl = threadIdx.x & 63, cg = threadIdx.x >> 6;

    const u16* hb = hn + ((long)b << 19);
    for (int c = cg; c < 128; c += 4)
        h_lds[sl][c] = bf2f(hb[(c << 12) + s0 + sl]);
    __syncthreads();

    const float4* w4 = (const float4*)w;
    u16* Qtb = Qt + ((long)b << 19);
    u16* Ktb = Kt + ((long)b << 19);
    u16* Vb  = Vv + ((long)b << 19);
    const float4* hrow = (const float4*)(&h_lds[sl][0]);
    int o0 = cg * 96;
    long srow = (long)(s0 + sl) * 128;

    for (int g4 = 0; g4 < 24; ++g4) {
        int o = o0 + g4 * 4;
        float a0 = bias[o], a1 = bias[o + 1], a2 = bias[o + 2], a3 = bias[o + 3];
        #pragma unroll 4
        for (int c4 = 0; c4 < 32; ++c4) {
            float4 hv = hrow[c4];
            float4 w0 = w4[(o + 0) * 32 + c4];
            float4 w1 = w4[(o + 1) * 32 + c4];
            float4 w2 = w4[(o + 2) * 32 + c4];
            float4 w3 = w4[(o + 3) * 32 + c4];
            a0 += hv.x * w0.x + hv.y * w0.y + hv.z * w0.z + hv.w * w0.w;
            a1 += hv.x * w1.x + hv.y * w1.y + hv.z * w1.z + hv.w * w1.w;
            a2 += hv.x * w2.x + hv.y * w2.y + hv.z * w2.z + hv.w * w2.w;
            a3 += hv.x * w3.x + hv.y * w3.y + hv.z * w3.z + hv.w * w3.w;
        }
        if (o < 128) {
            ushort4 val = { f2bf(a0), f2bf(a1), f2bf(a2), f2bf(a3) };
            *(ushort4*)&Qtb[srow + o] = val;
        } else if (o < 256) {
            ushort4 val = { f2bf(a0), f2bf(a1), f2bf(a2), f2bf(a3) };
            *(ushort4*)&Ktb[srow + (o - 128)] = val;
        } else {
            Vb[((long)(o - 256) << 12) + s0 + sl] = f2bf(a0);
            Vb[((long)(o - 255) << 12) + s0 + sl] = f2bf(a1);
            Vb[((long)(o - 254) << 12) + s0 + sl] = f2bf(a2);
            Vb[((long)(o - 253) << 12) + s0 + sl] = f2bf(a3);
        }
    }
}

// ============================================================
// Kernel 3: MFMA flash attention + final x*a multiply.
// 4 waves x 16 q-rows (QBLK=64). KV tiles of 64 keys staged via
// global_load_lds (linear dest, pre-swizzled source: chunk ^= row&7).
// Swapped QK^T (mfma(K,Q)) puts a whole q-row's scores in one lane's
// 16 regs; P^T B-frags for PV built by 16 shfls (no LDS round-trip).
// ============================================================
__global__ __launch_bounds__(256) void attn_kernel(
    const u16* __restrict__ Qt, const u16* __restrict__ Kt,
    const u16* __restrict__ Vv, const float* __restrict__ x,
    float* __restrict__ out)
{
    __shared__ u16 ldsK[8192];   // [64 s][16 chunks][8] swizzled
    __shared__ u16 ldsV[8192];   // [128 c][8 chunks][8] swizzled

    int tid = threadIdx.x, lane = tid & 63, wv = tid >> 6;
    int g = lane >> 4, t = lane & 15;
    int b = blockIdx.x >> 6, qb = blockIdx.x & 63;
    int s0 = qb << 6;
    int qrow = s0 + (wv << 4) + t;

    const u16* Qb = Qt + ((long)b << 19);
    const u16* Kb = Kt + ((long)b << 19);
    const u16* Vb = Vv + ((long)b << 19);

    // Q B-frags, register-resident across the whole KV loop
    bf16x8 qf[4];
    #pragma unroll
    for (int ks = 0; ks < 4; ++ks)
        qf[ks] = *(const bf16x8*)&Qb[(long)qrow * 128 + ks * 32 + g * 8];

    f32x4 acco[8];
    #pragma unroll
    for (int i = 0; i < 8; ++i) acco[i] = (f32x4){0.f, 0.f, 0.f, 0.f};
    float m = -1e30f, lsum = 0.f;

    for (int kt = 0; kt < 64; ++kt) {
        int sk = kt << 6;
        __syncthreads();
        // stage K (16KB) + V (16KB); wave wv covers segments 4wv..4wv+3 of each
        #pragma unroll
        for (int i = 0; i < 4; ++i) {
            int seg = wv * 4 + i;
            int idx = seg * 64 + lane;
            {   // K: LDS[s][ch] <- global chunk ch^(s&7)
                int s = idx >> 4, ch = idx & 15, gch = ch ^ (s & 7);
                gload16(Kb + (long)(sk + s) * 128 + gch * 8, &ldsK[seg * 512]);
            }
            {   // V: LDS[c][ch] <- global chunk ch^(c&7)
                int c = idx >> 3, ch = idx & 7, gch = ch ^ (c & 7);
                gload16(Vb + ((long)c << 12) + sk + gch * 8, &ldsV[seg * 512]);
            }
        }
        __syncthreads();

        // ---- QK^T: S^T tiles; lane ends with 16 scores for q-row t ----
        float p[16];
        #pragma unroll
        for (int st = 0; st < 4; ++st) {
            f32x4 acc = (f32x4){0.f, 0.f, 0.f, 0.f};
            int s = st * 16 + t;   // A-row (key) this lane supplies
            #pragma unroll
            for (int ks = 0; ks < 4; ++ks) {
                int ch = (g + 4 * ks) ^ (s & 7);
                bf16x8 kf = *(const bf16x8*)&ldsK[s * 128 + ch * 8];
                acc = __builtin_amdgcn_mfma_f32_16x16x32_bf16(kf, qf[ks], acc, 0, 0, 0);
            }
            #pragma unroll
            for (int r = 0; r < 4; ++r) p[st * 4 + r] = acc[r] * SCALE;
        }

        // ---- online softmax (row = q-row t, spread over 4 g-lanes) ----
        float mt = p[0];
        #pragma unroll
        for (int i = 1; i < 16; ++i) mt = fmaxf(mt, p[i]);
        mt = fmaxf(mt, __shfl_xor(mt, 16));
        mt = fmaxf(mt, __shfl_xor(mt, 32));
        float mnew = fmaxf(m, mt);
        float alpha = __expf(m - mnew);
        float ps = 0.f;
        #pragma unroll
        for (int i = 0; i < 16; ++i) { p[i] = __expf(p[i] - mnew); ps += p[i]; }
        ps += __shfl_xor(ps, 16);
        ps += __shfl_xor(ps, 32);
        lsum = lsum * alpha + ps;
        m = mnew;
        #pragma unroll
        for (int i = 0; i < 8; ++i) {
            acco[i][0] *= alpha; acco[i][1] *= alpha;
            acco[i][2] *= alpha; acco[i][3] *= alpha;
        }

        // ---- pack P to bf16 pairs, build P^T B-frags via shfl ----
        u32 w0[4], w1[4];
        #pragma unroll
        for (int st = 0; st < 4; ++st) {
            w0[st] = (u32)f2bf(p[st * 4 + 0]) | ((u32)f2bf(p[st * 4 + 1]) << 16);
            w1[st] = (u32)f2bf(p[st * 4 + 2]) | ((u32)f2bf(p[st * 4 + 3]) << 16);
        }
        int base = t + ((lane & 16) << 1);   // t + 32*(g&1)
        bool hi = (lane & 32) != 0;          // g>>1
        union { u32 u[4]; bf16x8 v; } pa0, pa1;
        #pragma unroll
        for (int j2 = 0; j2 < 4; ++j2) {
            int src = base + ((j2 & 2) << 3);   // + 16*(j2>>1)
            u32 q0 = (u32)__shfl((int)((j2 & 1) ? w1[0] : w0[0]), src);
            u32 q1 = (u32)__shfl((int)((j2 & 1) ? w1[1] : w0[1]), src);
            u32 q2 = (u32)__shfl((int)((j2 & 1) ? w1[2] : w0[2]), src);
            u32 q3 = (u32)__shfl((int)((j2 & 1) ? w1[3] : w0[3]), src);
            pa0.u[j2] = hi ? q1 : q0;
            pa1.u[j2] = hi ? q3 : q2;
        }

        // ---- PV: O^T[c][t] += V * P^T ----
        #pragma unroll
        for (int ct = 0; ct < 8; ++ct) {
            int c = ct * 16 + t;   // A-row (channel) this lane supplies
            {
                int ch = g ^ (c & 7);
                bf16x8 vf = *(const bf16x8*)&ldsV[c * 64 + ch * 8];
                acco[ct] = __builtin_amdgcn_mfma_f32_16x16x32_bf16(vf, pa0.v, acco[ct], 0, 0, 0);
            }
            {
                int ch = (g + 4) ^ (c & 7);
                bf16x8 vf = *(const bf16x8*)&ldsV[c * 64 + ch * 8];
                acco[ct] = __builtin_amdgcn_mfma_f32_16x16x32_bf16(vf, pa1.v, acco[ct], 0, 0, 0);
            }
        }
    }

    // ---- epilogue: out = x * (O / l) ----
    float inv = 1.0f / lsum;
    #pragma unroll
    for (int ct = 0; ct < 8; ++ct) {
        #pragma unroll
        for (int r = 0; r < 4; ++r) {
            int c = ct * 16 + g * 4 + r;
            long gi = (((long)(b * 128 + c)) << 12) + s0 + (wv << 4) + t;
            out[gi] = x[gi] * acco[ct][r] * inv;
        }
    }
}

// ============================================================
extern "C" void kernel_launch(void* const* d_in, const int* in_sizes, int n_in,
                              void* d_out, int out_size, void* d_ws, size_t ws_size,
                              hipStream_t stream)
{
    const float* x    = (const float*)d_in[0];
    const float* gw   = (const float*)d_in[1];
    const float* gb   = (const float*)d_in[2];
    const float* w    = (const float*)d_in[3];
    const float* bias = (const float*)d_in[4];
    float* out = (float*)d_out;

    u16* hn = (u16*)d_ws;                        // [8][128][4096] bf16 = 8 MB
    u16* Qt = hn + (size_t)8 * 128 * 4096;       // [8][4096][128] bf16 = 8 MB
    u16* Kt = Qt + (size_t)8 * 4096 * 128;       // [8][4096][128] bf16 = 8 MB
    u16* Vv = Kt + (size_t)8 * 4096 * 128;       // [8][128][4096] bf16 = 8 MB

    gn_kernel<<<256, 256, 0, stream>>>(x, gw, gb, hn);
    qkv_kernel<<<512, 256, 0, stream>>>(hn, w, bias, Qt, Kt, Vv);
    attn_kernel<<<512, 256, 0, stream>>>(Qt, Kt, Vv, x, out);
}

// Round 3
// 198.810 us; speedup vs baseline: 11.3167x; 1.7276x over previous
//
#include <hip/hip_runtime.h>
#include <stdint.h>

typedef unsigned short u16;
typedef unsigned int   u32;
typedef __attribute__((ext_vector_type(8))) short bf16x8;
typedef __attribute__((ext_vector_type(8))) unsigned short u16x8;
typedef __attribute__((ext_vector_type(4))) float f32x4;

#define SCALE 0.08838834764831845f

__device__ __forceinline__ float bf2f(u16 u) {
    union { u32 i; float f; } t; t.i = ((u32)u) << 16; return t.f;
}
__device__ __forceinline__ u16 f2bf(float f) {
    union { u32 i; float f; } t; t.f = f;
    u32 b = t.i;
    return (u16)((b + 0x7fffu + ((b >> 16) & 1u)) >> 16);
}

// async global->LDS, 16B per lane, linear LDS dest (wave-uniform base + lane*16)
__device__ __forceinline__ void gload16(const u16* g, u16* l) {
    __builtin_amdgcn_global_load_lds(
        (const __attribute__((address_space(1))) void*)g,
        (__attribute__((address_space(3))) void*)l, 16, 0, 0);
}

// ============================================================
// Kernel 0: GroupNorm stats -> per-channel affine (gp = gamma*rstd,
// bp = beta - mean*gamma*rstd), per batch. One block per (b, g).
// ============================================================
__global__ __launch_bounds__(256) void stats_kernel(
    const float* __restrict__ x, const float* __restrict__ gw,
    const float* __restrict__ gb, float* __restrict__ gp, float* __restrict__ bp)
{
    int b = blockIdx.x >> 5, g = blockIdx.x & 31;
    long base = ((long)(b * 128 + g * 4)) << 12;
    const float4* x4 = (const float4*)(x + base);

    float s = 0.f, ss = 0.f;
    for (int i = threadIdx.x; i < 4096; i += 256) {
        float4 v = x4[i];
        s  += v.x + v.y + v.z + v.w;
        ss += v.x * v.x + v.y * v.y + v.z * v.z + v.w * v.w;
    }
    #pragma unroll
    for (int off = 32; off > 0; off >>= 1) {
        s  += __shfl_xor(s,  off);
        ss += __shfl_xor(ss, off);
    }
    __shared__ float red[8];
    int wid = threadIdx.x >> 6;
    if ((threadIdx.x & 63) == 0) { red[wid * 2] = s; red[wid * 2 + 1] = ss; }
    __syncthreads();
    s  = red[0] + red[2] + red[4] + red[6];
    ss = red[1] + red[3] + red[5] + red[7];

    float mean = s * (1.f / 16384.f);
    float var  = ss * (1.f / 16384.f) - mean * mean;
    float rs   = rsqrtf(var + 1e-5f);

    if (threadIdx.x < 4) {
        int c = g * 4 + threadIdx.x;
        float gamma = gw[c] * rs;
        gp[b * 128 + c] = gamma;
        bp[b * 128 + c] = gb[c] - mean * gamma;
    }
}

// ============================================================
// Kernel 0b: w fp32 -> bf16
// ============================================================
__global__ __launch_bounds__(256) void wconv_kernel(
    const float* __restrict__ w, u16* __restrict__ wbf)
{
    int idx = (blockIdx.x * 256 + threadIdx.x) * 4;
    float4 v = *(const float4*)&w[idx];
    ushort4 o = { f2bf(v.x), f2bf(v.y), f2bf(v.z), f2bf(v.w) };
    *(ushort4*)&wbf[idx] = o;
}

// ============================================================
// Kernel 1: apply GN + transpose. Reads x [b][c][s] coalesced,
// writes hn [b][s][c] bf16 coalesced via swizzled LDS bounce.
// Block = (b, 128-s tile). LDS tile [128 s][16 chunks] with
// chunk slot = CH ^ (s&15).
// ============================================================
__global__ __launch_bounds__(256) void apply_kernel(
    const float* __restrict__ x, const float* __restrict__ gp,
    const float* __restrict__ bp, u16* __restrict__ hn)
{
    __shared__ u16 ldsT[128 * 128];   // 32 KB
    __shared__ float gpl[128], bpl[128];
    int b = blockIdx.x >> 5, st = blockIdx.x & 31;
    int s0 = st << 7;
    int t = threadIdx.x;
    if (t < 128) { gpl[t] = gp[b * 128 + t]; bpl[t] = bp[b * 128 + t]; }
    __syncthreads();

    const float* xb = x + ((long)b << 19);
    int sl = t & 127, chalf = t >> 7;
    #pragma unroll
    for (int c8 = 0; c8 < 8; ++c8) {
        int CH = chalf * 8 + c8;
        u16 tmp[8];
        #pragma unroll
        for (int j = 0; j < 8; ++j) {
            int c = CH * 8 + j;
            float v = xb[((long)c << 12) + s0 + sl];
            tmp[j] = f2bf(v * gpl[c] + bpl[c]);
        }
        *(u16x8*)&ldsT[sl * 128 + ((CH ^ (sl & 15)) << 3)] = *(u16x8*)tmp;
    }
    __syncthreads();

    u16* hnb = hn + ((long)b << 19);
    int s = t >> 1, h = t & 1;
    #pragma unroll
    for (int i = 0; i < 8; ++i) {
        int CH = h * 8 + i;
        u16x8 v = *(u16x8*)&ldsT[s * 128 + ((CH ^ (s & 15)) << 3)];
        *(u16x8*)&hnb[(long)(s0 + s) * 128 + CH * 8] = v;
    }
}

// ============================================================
// Kernel 2: QKV projection via MFMA.
// Block = (b, 64-s tile), 4 waves; wave wv owns 16 s, all 384 o.
// h-tile [64 s][16 chunks] staged via gload16 (source chunk ^ (s&15)).
// Q/K: D[s][o] = mfma(hfrag, wfrag)  -> Qt/Kt [s][128] direct.
// V:   D[o][s] = mfma(wfrag, hfrag)  -> Vv [c][s] direct.
// ============================================================
__global__ __launch_bounds__(256) void qkvm_kernel(
    const u16* __restrict__ hn, const u16* __restrict__ wbf,
    const float* __restrict__ bias,
    u16* __restrict__ Qt, u16* __restrict__ Kt, u16* __restrict__ Vv)
{
    __shared__ u16 ldsH[64 * 128];   // 16 KB
    int tid = threadIdx.x, lane = tid & 63, wv = tid >> 6;
    int g = lane >> 4, t = lane & 15;
    int b = blockIdx.x >> 6, stile = blockIdx.x & 63;
    int s0 = stile << 6;

    const u16* hnb = hn + ((long)b << 19);
    #pragma unroll
    for (int i = 0; i < 4; ++i) {
        int seg = wv * 4 + i;
        int n = seg * 64 + lane;
        int s = n >> 4, SL = n & 15;
        int gch = SL ^ (s & 15);
        gload16(hnb + (long)(s0 + s) * 128 + gch * 8, &ldsH[seg * 512]);
    }
    __syncthreads();

    // h fragments: row s = 16wv + t, k-run c = 32ks + 8g
    bf16x8 hf[4];
    int slq = (wv << 4) + t;
    #pragma unroll
    for (int ks = 0; ks < 4; ++ks)
        hf[ks] = *(const bf16x8*)&ldsH[slq * 128 + ((((ks << 2) + g) ^ t) << 3)];

    u16* Qtb = Qt + ((long)b << 19);
    u16* Ktb = Kt + ((long)b << 19);
    u16* Vb  = Vv + ((long)b << 19);
    int srow = s0 + (wv << 4) + (g << 2);

    // ---- Q tiles (o = 0..128) ----
    #pragma unroll
    for (int ot = 0; ot < 8; ++ot) {
        bf16x8 wf[4];
        #pragma unroll
        for (int ks = 0; ks < 4; ++ks)
            wf[ks] = *(const bf16x8*)&wbf[(ot * 16 + t) * 128 + ks * 32 + g * 8];
        float bv = bias[ot * 16 + t];
        f32x4 acc = (f32x4){bv, bv, bv, bv};
        #pragma unroll
        for (int ks = 0; ks < 4; ++ks)
            acc = __builtin_amdgcn_mfma_f32_16x16x32_bf16(hf[ks], wf[ks], acc, 0, 0, 0);
        #pragma unroll
        for (int r = 0; r < 4; ++r)
            Qtb[(long)(srow + r) * 128 + ot * 16 + t] = f2bf(acc[r]);
    }
    // ---- K tiles (o = 128..256) ----
    #pragma unroll
    for (int ot = 8; ot < 16; ++ot) {
        bf16x8 wf[4];
        #pragma unroll
        for (int ks = 0; ks < 4; ++ks)
            wf[ks] = *(const bf16x8*)&wbf[(ot * 16 + t) * 128 + ks * 32 + g * 8];
        float bv = bias[ot * 16 + t];
        f32x4 acc = (f32x4){bv, bv, bv, bv};
        #pragma unroll
        for (int ks = 0; ks < 4; ++ks)
            acc = __builtin_amdgcn_mfma_f32_16x16x32_bf16(hf[ks], wf[ks], acc, 0, 0, 0);
        #pragma unroll
        for (int r = 0; r < 4; ++r)
            Ktb[(long)(srow + r) * 128 + (ot - 8) * 16 + t] = f2bf(acc[r]);
    }
    // ---- V tiles (o = 256..384), swapped operands -> D[o][s] ----
    #pragma unroll
    for (int ot = 16; ot < 24; ++ot) {
        bf16x8 wf[4];
        #pragma unroll
        for (int ks = 0; ks < 4; ++ks)
            wf[ks] = *(const bf16x8*)&wbf[(ot * 16 + t) * 128 + ks * 32 + g * 8];
        float4 b4 = *(const float4*)&bias[ot * 16 + (g << 2)];
        f32x4 acc = (f32x4){b4.x, b4.y, b4.z, b4.w};
        #pragma unroll
        for (int ks = 0; ks < 4; ++ks)
            acc = __builtin_amdgcn_mfma_f32_16x16x32_bf16(wf[ks], hf[ks], acc, 0, 0, 0);
        #pragma unroll
        for (int r = 0; r < 4; ++r) {
            int cv = (ot - 16) * 16 + (g << 2) + r;
            Vb[((long)cv << 12) + s0 + (wv << 4) + t] = f2bf(acc[r]);
        }
    }
}

// ============================================================
// Kernel 3: MFMA flash attention + final x*a multiply (unchanged).
// ============================================================
__global__ __launch_bounds__(256) void attn_kernel(
    const u16* __restrict__ Qt, const u16* __restrict__ Kt,
    const u16* __restrict__ Vv, const float* __restrict__ x,
    float* __restrict__ out)
{
    __shared__ u16 ldsK[8192];   // [64 s][16 chunks][8] swizzled
    __shared__ u16 ldsV[8192];   // [128 c][8 chunks][8] swizzled

    int tid = threadIdx.x, lane = tid & 63, wv = tid >> 6;
    int g = lane >> 4, t = lane & 15;
    int b = blockIdx.x >> 6, qb = blockIdx.x & 63;
    int s0 = qb << 6;
    int qrow = s0 + (wv << 4) + t;

    const u16* Qb = Qt + ((long)b << 19);
    const u16* Kb = Kt + ((long)b << 19);
    const u16* Vb = Vv + ((long)b << 19);

    bf16x8 qf[4];
    #pragma unroll
    for (int ks = 0; ks < 4; ++ks)
        qf[ks] = *(const bf16x8*)&Qb[(long)qrow * 128 + ks * 32 + g * 8];

    f32x4 acco[8];
    #pragma unroll
    for (int i = 0; i < 8; ++i) acco[i] = (f32x4){0.f, 0.f, 0.f, 0.f};
    float m = -1e30f, lsum = 0.f;

    for (int kt = 0; kt < 64; ++kt) {
        int sk = kt << 6;
        __syncthreads();
        #pragma unroll
        for (int i = 0; i < 4; ++i) {
            int seg = wv * 4 + i;
            int idx = seg * 64 + lane;
            {   // K: LDS[s][ch] <- global chunk ch^(s&7)
                int s = idx >> 4, ch = idx & 15, gch = ch ^ (s & 7);
                gload16(Kb + (long)(sk + s) * 128 + gch * 8, &ldsK[seg * 512]);
            }
            {   // V: LDS[c][ch] <- global chunk ch^(c&7)
                int c = idx >> 3, ch = idx & 7, gch = ch ^ (c & 7);
                gload16(Vb + ((long)c << 12) + sk + gch * 8, &ldsV[seg * 512]);
            }
        }
        __syncthreads();

        // ---- QK^T ----
        float p[16];
        #pragma unroll
        for (int st = 0; st < 4; ++st) {
            f32x4 acc = (f32x4){0.f, 0.f, 0.f, 0.f};
            int s = st * 16 + t;
            #pragma unroll
            for (int ks = 0; ks < 4; ++ks) {
                int ch = (g + 4 * ks) ^ (s & 7);
                bf16x8 kf = *(const bf16x8*)&ldsK[s * 128 + ch * 8];
                acc = __builtin_amdgcn_mfma_f32_16x16x32_bf16(kf, qf[ks], acc, 0, 0, 0);
            }
            #pragma unroll
            for (int r = 0; r < 4; ++r) p[st * 4 + r] = acc[r] * SCALE;
        }

        // ---- online softmax ----
        float mt = p[0];
        #pragma unroll
        for (int i = 1; i < 16; ++i) mt = fmaxf(mt, p[i]);
        mt = fmaxf(mt, __shfl_xor(mt, 16));
        mt = fmaxf(mt, __shfl_xor(mt, 32));
        float mnew = fmaxf(m, mt);
        float alpha = __expf(m - mnew);
        float ps = 0.f;
        #pragma unroll
        for (int i = 0; i < 16; ++i) { p[i] = __expf(p[i] - mnew); ps += p[i]; }
        ps += __shfl_xor(ps, 16);
        ps += __shfl_xor(ps, 32);
        lsum = lsum * alpha + ps;
        m = mnew;
        #pragma unroll
        for (int i = 0; i < 8; ++i) {
            acco[i][0] *= alpha; acco[i][1] *= alpha;
            acco[i][2] *= alpha; acco[i][3] *= alpha;
        }

        // ---- pack P, build P^T B-frags via shfl ----
        u32 w0[4], w1[4];
        #pragma unroll
        for (int st = 0; st < 4; ++st) {
            w0[st] = (u32)f2bf(p[st * 4 + 0]) | ((u32)f2bf(p[st * 4 + 1]) << 16);
            w1[st] = (u32)f2bf(p[st * 4 + 2]) | ((u32)f2bf(p[st * 4 + 3]) << 16);
        }
        int base = t + ((lane & 16) << 1);
        bool hi = (lane & 32) != 0;
        union { u32 u[4]; bf16x8 v; } pa0, pa1;
        #pragma unroll
        for (int j2 = 0; j2 < 4; ++j2) {
            int src = base + ((j2 & 2) << 3);
            u32 q0 = (u32)__shfl((int)((j2 & 1) ? w1[0] : w0[0]), src);
            u32 q1 = (u32)__shfl((int)((j2 & 1) ? w1[1] : w0[1]), src);
            u32 q2 = (u32)__shfl((int)((j2 & 1) ? w1[2] : w0[2]), src);
            u32 q3 = (u32)__shfl((int)((j2 & 1) ? w1[3] : w0[3]), src);
            pa0.u[j2] = hi ? q1 : q0;
            pa1.u[j2] = hi ? q3 : q2;
        }

        // ---- PV ----
        #pragma unroll
        for (int ct = 0; ct < 8; ++ct) {
            int c = ct * 16 + t;
            {
                int ch = g ^ (c & 7);
                bf16x8 vf = *(const bf16x8*)&ldsV[c * 64 + ch * 8];
                acco[ct] = __builtin_amdgcn_mfma_f32_16x16x32_bf16(vf, pa0.v, acco[ct], 0, 0, 0);
            }
            {
                int ch = (g + 4) ^ (c & 7);
                bf16x8 vf = *(const bf16x8*)&ldsV[c * 64 + ch * 8];
                acco[ct] = __builtin_amdgcn_mfma_f32_16x16x32_bf16(vf, pa1.v, acco[ct], 0, 0, 0);
            }
        }
    }

    // ---- epilogue: out = x * (O / l) ----
    float inv = 1.0f / lsum;
    #pragma unroll
    for (int ct = 0; ct < 8; ++ct) {
        #pragma unroll
        for (int r = 0; r < 4; ++r) {
            int c = ct * 16 + g * 4 + r;
            long gi = (((long)(b * 128 + c)) << 12) + s0 + (wv << 4) + t;
            out[gi] = x[gi] * acco[ct][r] * inv;
        }
    }
}

// ============================================================
extern "C" void kernel_launch(void* const* d_in, const int* in_sizes, int n_in,
                              void* d_out, int out_size, void* d_ws, size_t ws_size,
                              hipStream_t stream)
{
    const float* x    = (const float*)d_in[0];
    const float* gw   = (const float*)d_in[1];
    const float* gb   = (const float*)d_in[2];
    const float* w    = (const float*)d_in[3];
    const float* bias = (const float*)d_in[4];
    float* out = (float*)d_out;

    u16* hn  = (u16*)d_ws;                        // [8][4096][128] bf16 = 8 MB
    u16* Qt  = hn + (size_t)8 * 4096 * 128;       // [8][4096][128] bf16 = 8 MB
    u16* Kt  = Qt + (size_t)8 * 4096 * 128;       // [8][4096][128] bf16 = 8 MB
    u16* Vv  = Kt + (size_t)8 * 4096 * 128;       // [8][128][4096] bf16 = 8 MB
    u16* wbf = Vv + (size_t)8 * 128 * 4096;       // [384][128] bf16 = 96 KB
    float* gp = (float*)(wbf + (size_t)384 * 128); // [8][128]
    float* bp = gp + 1024;                         // [8][128]

    stats_kernel<<<256, 256, 0, stream>>>(x, gw, gb, gp, bp);
    wconv_kernel<<<48, 256, 0, stream>>>(w, wbf);
    apply_kernel<<<256, 256, 0, stream>>>(x, gp, bp, hn);
    qkvm_kernel<<<512, 256, 0, stream>>>(hn, wbf, bias, Qt, Kt, Vv);
    attn_kernel<<<512, 256, 0, stream>>>(Qt, Kt, Vv, x, out);
}

// Round 4
// 194.546 us; speedup vs baseline: 11.5647x; 1.0219x over previous
//
#include <hip/hip_runtime.h>
#include <hip/hip_bf16.h>
#include <stdint.h>

typedef unsigned short u16;
typedef unsigned int   u32;
typedef __attribute__((ext_vector_type(8))) short bf16x8;
typedef __attribute__((ext_vector_type(8))) unsigned short u16x8;
typedef __attribute__((ext_vector_type(4))) float f32x4;

#define SCALE 0.08838834764831845f
// SCALE * log2(e): scores scaled directly into exp2 domain
#define SC2 0.1275174475f

__device__ __forceinline__ float bf2f(u16 u) {
    union { u32 i; float f; } t; t.i = ((u32)u) << 16; return t.f;
}
__device__ __forceinline__ u16 f2bf(float f) {
    union { u32 i; float f; } t; t.f = f;
    u32 b = t.i;
    return (u16)((b + 0x7fffu + ((b >> 16) & 1u)) >> 16);
}
// pack two floats to bf16 pair (compiler emits v_cvt_pk_bf16_f32)
__device__ __forceinline__ u32 packbf(float a, float b) {
    union { __hip_bfloat162 h; u32 u; } c;
    c.h = __float22bfloat162_rn(float2{a, b});
    return c.u;
}

// async global->LDS, 16B per lane, linear LDS dest (wave-uniform base + lane*16)
__device__ __forceinline__ void gload16(const u16* g, u16* l) {
    __builtin_amdgcn_global_load_lds(
        (const __attribute__((address_space(1))) void*)g,
        (__attribute__((address_space(3))) void*)l, 16, 0, 0);
}

// ============================================================
// Kernel 0: GroupNorm stats -> per-channel affine tables.
// ============================================================
__global__ __launch_bounds__(256) void stats_kernel(
    const float* __restrict__ x, const float* __restrict__ gw,
    const float* __restrict__ gb, float* __restrict__ gp, float* __restrict__ bp)
{
    int b = blockIdx.x >> 5, g = blockIdx.x & 31;
    long base = ((long)(b * 128 + g * 4)) << 12;
    const float4* x4 = (const float4*)(x + base);

    float s = 0.f, ss = 0.f;
    for (int i = threadIdx.x; i < 4096; i += 256) {
        float4 v = x4[i];
        s  += v.x + v.y + v.z + v.w;
        ss += v.x * v.x + v.y * v.y + v.z * v.z + v.w * v.w;
    }
    #pragma unroll
    for (int off = 32; off > 0; off >>= 1) {
        s  += __shfl_xor(s,  off);
        ss += __shfl_xor(ss, off);
    }
    __shared__ float red[8];
    int wid = threadIdx.x >> 6;
    if ((threadIdx.x & 63) == 0) { red[wid * 2] = s; red[wid * 2 + 1] = ss; }
    __syncthreads();
    s  = red[0] + red[2] + red[4] + red[6];
    ss = red[1] + red[3] + red[5] + red[7];

    float mean = s * (1.f / 16384.f);
    float var  = ss * (1.f / 16384.f) - mean * mean;
    float rs   = rsqrtf(var + 1e-5f);

    if (threadIdx.x < 4) {
        int c = g * 4 + threadIdx.x;
        float gamma = gw[c] * rs;
        gp[b * 128 + c] = gamma;
        bp[b * 128 + c] = gb[c] - mean * gamma;
    }
}

// ============================================================
// Kernel 0b: w fp32 -> bf16
// ============================================================
__global__ __launch_bounds__(256) void wconv_kernel(
    const float* __restrict__ w, u16* __restrict__ wbf)
{
    int idx = (blockIdx.x * 256 + threadIdx.x) * 4;
    float4 v = *(const float4*)&w[idx];
    ushort4 o = { f2bf(v.x), f2bf(v.y), f2bf(v.z), f2bf(v.w) };
    *(ushort4*)&wbf[idx] = o;
}

// ============================================================
// Kernel 1: apply GN + transpose -> hn [b][s][c] bf16.
// ============================================================
__global__ __launch_bounds__(256) void apply_kernel(
    const float* __restrict__ x, const float* __restrict__ gp,
    const float* __restrict__ bp, u16* __restrict__ hn)
{
    __shared__ u16 ldsT[128 * 128];   // 32 KB
    __shared__ float gpl[128], bpl[128];
    int b = blockIdx.x >> 5, st = blockIdx.x & 31;
    int s0 = st << 7;
    int t = threadIdx.x;
    if (t < 128) { gpl[t] = gp[b * 128 + t]; bpl[t] = bp[b * 128 + t]; }
    __syncthreads();

    const float* xb = x + ((long)b << 19);
    int sl = t & 127, chalf = t >> 7;
    #pragma unroll
    for (int c8 = 0; c8 < 8; ++c8) {
        int CH = chalf * 8 + c8;
        u16 tmp[8];
        #pragma unroll
        for (int j = 0; j < 8; ++j) {
            int c = CH * 8 + j;
            float v = xb[((long)c << 12) + s0 + sl];
            tmp[j] = f2bf(v * gpl[c] + bpl[c]);
        }
        *(u16x8*)&ldsT[sl * 128 + ((CH ^ (sl & 15)) << 3)] = *(u16x8*)tmp;
    }
    __syncthreads();

    u16* hnb = hn + ((long)b << 19);
    int s = t >> 1, h = t & 1;
    #pragma unroll
    for (int i = 0; i < 8; ++i) {
        int CH = h * 8 + i;
        u16x8 v = *(u16x8*)&ldsT[s * 128 + ((CH ^ (s & 15)) << 3)];
        *(u16x8*)&hnb[(long)(s0 + s) * 128 + CH * 8] = v;
    }
}

// ============================================================
// Kernel 2: QKV projection via MFMA (unchanged from round 3).
// ============================================================
__global__ __launch_bounds__(256) void qkvm_kernel(
    const u16* __restrict__ hn, const u16* __restrict__ wbf,
    const float* __restrict__ bias,
    u16* __restrict__ Qt, u16* __restrict__ Kt, u16* __restrict__ Vv)
{
    __shared__ u16 ldsH[64 * 128];   // 16 KB
    int tid = threadIdx.x, lane = tid & 63, wv = tid >> 6;
    int g = lane >> 4, t = lane & 15;
    int b = blockIdx.x >> 6, stile = blockIdx.x & 63;
    int s0 = stile << 6;

    const u16* hnb = hn + ((long)b << 19);
    #pragma unroll
    for (int i = 0; i < 4; ++i) {
        int seg = wv * 4 + i;
        int n = seg * 64 + lane;
        int s = n >> 4, SL = n & 15;
        int gch = SL ^ (s & 15);
        gload16(hnb + (long)(s0 + s) * 128 + gch * 8, &ldsH[seg * 512]);
    }
    __syncthreads();

    bf16x8 hf[4];
    int slq = (wv << 4) + t;
    #pragma unroll
    for (int ks = 0; ks < 4; ++ks)
        hf[ks] = *(const bf16x8*)&ldsH[slq * 128 + ((((ks << 2) + g) ^ t) << 3)];

    u16* Qtb = Qt + ((long)b << 19);
    u16* Ktb = Kt + ((long)b << 19);
    u16* Vb  = Vv + ((long)b << 19);
    int srow = s0 + (wv << 4) + (g << 2);

    #pragma unroll
    for (int ot = 0; ot < 8; ++ot) {
        bf16x8 wf[4];
        #pragma unroll
        for (int ks = 0; ks < 4; ++ks)
            wf[ks] = *(const bf16x8*)&wbf[(ot * 16 + t) * 128 + ks * 32 + g * 8];
        float bv = bias[ot * 16 + t];
        f32x4 acc = (f32x4){bv, bv, bv, bv};
        #pragma unroll
        for (int ks = 0; ks < 4; ++ks)
            acc = __builtin_amdgcn_mfma_f32_16x16x32_bf16(hf[ks], wf[ks], acc, 0, 0, 0);
        #pragma unroll
        for (int r = 0; r < 4; ++r)
            Qtb[(long)(srow + r) * 128 + ot * 16 + t] = f2bf(acc[r]);
    }
    #pragma unroll
    for (int ot = 8; ot < 16; ++ot) {
        bf16x8 wf[4];
        #pragma unroll
        for (int ks = 0; ks < 4; ++ks)
            wf[ks] = *(const bf16x8*)&wbf[(ot * 16 + t) * 128 + ks * 32 + g * 8];
        float bv = bias[ot * 16 + t];
        f32x4 acc = (f32x4){bv, bv, bv, bv};
        #pragma unroll
        for (int ks = 0; ks < 4; ++ks)
            acc = __builtin_amdgcn_mfma_f32_16x16x32_bf16(hf[ks], wf[ks], acc, 0, 0, 0);
        #pragma unroll
        for (int r = 0; r < 4; ++r)
            Ktb[(long)(srow + r) * 128 + (ot - 8) * 16 + t] = f2bf(acc[r]);
    }
    #pragma unroll
    for (int ot = 16; ot < 24; ++ot) {
        bf16x8 wf[4];
        #pragma unroll
        for (int ks = 0; ks < 4; ++ks)
            wf[ks] = *(const bf16x8*)&wbf[(ot * 16 + t) * 128 + ks * 32 + g * 8];
        float4 b4 = *(const float4*)&bias[ot * 16 + (g << 2)];
        f32x4 acc = (f32x4){b4.x, b4.y, b4.z, b4.w};
        #pragma unroll
        for (int ks = 0; ks < 4; ++ks)
            acc = __builtin_amdgcn_mfma_f32_16x16x32_bf16(wf[ks], hf[ks], acc, 0, 0, 0);
        #pragma unroll
        for (int r = 0; r < 4; ++r) {
            int cv = (ot - 16) * 16 + (g << 2) + r;
            Vb[((long)cv << 12) + s0 + (wv << 4) + t] = f2bf(acc[r]);
        }
    }
}

// ============================================================
// Kernel 3: MFMA flash attention + final x*a multiply.
// Round-4 changes: double-buffered KV staging (prefetch overlapped
// with compute, ONE barrier/iter), setprio around MFMA clusters,
// exp2-domain softmax, defer-max (THR=12), cvt_pk P-packing.
// ============================================================
__global__ __launch_bounds__(256) void attn_kernel(
    const u16* __restrict__ Qt, const u16* __restrict__ Kt,
    const u16* __restrict__ Vv, const float* __restrict__ x,
    float* __restrict__ out)
{
    __shared__ u16 ldsK[2][8192];   // [64 s][16 chunks][8] swizzled, x2
    __shared__ u16 ldsV[2][8192];   // [128 c][8 chunks][8] swizzled, x2

    int tid = threadIdx.x, lane = tid & 63, wv = tid >> 6;
    int g = lane >> 4, t = lane & 15;
    int b = blockIdx.x >> 6, qb = blockIdx.x & 63;
    int s0 = qb << 6;
    int qrow = s0 + (wv << 4) + t;

    const u16* Qb = Qt + ((long)b << 19);
    const u16* Kb = Kt + ((long)b << 19);
    const u16* Vb = Vv + ((long)b << 19);

    bf16x8 qf[4];
    #pragma unroll
    for (int ks = 0; ks < 4; ++ks)
        qf[ks] = *(const bf16x8*)&Qb[(long)qrow * 128 + ks * 32 + g * 8];

    f32x4 acco[8];
    #pragma unroll
    for (int i = 0; i < 8; ++i) acco[i] = (f32x4){0.f, 0.f, 0.f, 0.f};
    float m = -1e30f, lsum = 0.f;

    // stage K (16KB) + V (16KB) for tile kt into buffer buf
    auto STAGE = [&](int buf, int kt) {
        int sk = kt << 6;
        #pragma unroll
        for (int i = 0; i < 4; ++i) {
            int seg = wv * 4 + i;
            int idx = seg * 64 + lane;
            {   // K: LDS[s][ch] <- global chunk ch^(s&7)
                int s = idx >> 4, ch = idx & 15, gch = ch ^ (s & 7);
                gload16(Kb + (long)(sk + s) * 128 + gch * 8, &ldsK[buf][seg * 512]);
            }
            {   // V: LDS[c][ch] <- global chunk ch^(c&7)
                int c = idx >> 3, ch = idx & 7, gch = ch ^ (c & 7);
                gload16(Vb + ((long)c << 12) + sk + gch * 8, &ldsV[buf][seg * 512]);
            }
        }
    };

    STAGE(0, 0);
    __syncthreads();   // vmcnt(0) drain of tile 0 (+ Q frag loads)
    int cur = 0;

    for (int kt = 0; kt < 64; ++kt) {
        // prefetch next tile into the other buffer; latency hides under compute
        if (kt < 63) STAGE(cur ^ 1, kt + 1);

        // ---- QK^T from ldsK[cur] ----
        const u16* lK = ldsK[cur];
        const u16* lV = ldsV[cur];
        float p2[16];
        __builtin_amdgcn_s_setprio(1);
        #pragma unroll
        for (int st = 0; st < 4; ++st) {
            f32x4 acc = (f32x4){0.f, 0.f, 0.f, 0.f};
            int s = st * 16 + t;
            #pragma unroll
            for (int ks = 0; ks < 4; ++ks) {
                int ch = (g + 4 * ks) ^ (s & 7);
                bf16x8 kf = *(const bf16x8*)&lK[s * 128 + ch * 8];
                acc = __builtin_amdgcn_mfma_f32_16x16x32_bf16(kf, qf[ks], acc, 0, 0, 0);
            }
            #pragma unroll
            for (int r = 0; r < 4; ++r) p2[st * 4 + r] = acc[r] * SC2;
        }
        __builtin_amdgcn_s_setprio(0);

        // ---- online softmax in exp2 domain, defer-max ----
        float pmax = p2[0];
        #pragma unroll
        for (int i = 1; i < 16; ++i) pmax = fmaxf(pmax, p2[i]);
        pmax = fmaxf(pmax, __shfl_xor(pmax, 16));
        pmax = fmaxf(pmax, __shfl_xor(pmax, 32));
        if (!__all(pmax - m <= 12.0f)) {
            float mnew = fmaxf(m, pmax);
            float alpha = exp2f(m - mnew);
            lsum *= alpha;
            #pragma unroll
            for (int i = 0; i < 8; ++i) {
                acco[i][0] *= alpha; acco[i][1] *= alpha;
                acco[i][2] *= alpha; acco[i][3] *= alpha;
            }
            m = mnew;
        }
        float p[16];
        float ps = 0.f;
        #pragma unroll
        for (int i = 0; i < 16; ++i) { p[i] = exp2f(p2[i] - m); ps += p[i]; }
        ps += __shfl_xor(ps, 16);
        ps += __shfl_xor(ps, 32);
        lsum += ps;

        // ---- pack P to bf16 pairs, build P^T B-frags via shfl ----
        u32 w0[4], w1[4];
        #pragma unroll
        for (int st = 0; st < 4; ++st) {
            w0[st] = packbf(p[st * 4 + 0], p[st * 4 + 1]);
            w1[st] = packbf(p[st * 4 + 2], p[st * 4 + 3]);
        }
        int base = t + ((lane & 16) << 1);
        bool hi = (lane & 32) != 0;
        union { u32 u[4]; bf16x8 v; } pa0, pa1;
        #pragma unroll
        for (int j2 = 0; j2 < 4; ++j2) {
            int src = base + ((j2 & 2) << 3);
            u32 q0 = (u32)__shfl((int)((j2 & 1) ? w1[0] : w0[0]), src);
            u32 q1 = (u32)__shfl((int)((j2 & 1) ? w1[1] : w0[1]), src);
            u32 q2 = (u32)__shfl((int)((j2 & 1) ? w1[2] : w0[2]), src);
            u32 q3 = (u32)__shfl((int)((j2 & 1) ? w1[3] : w0[3]), src);
            pa0.u[j2] = hi ? q1 : q0;
            pa1.u[j2] = hi ? q3 : q2;
        }

        // ---- PV from ldsV[cur] ----
        __builtin_amdgcn_s_setprio(1);
        #pragma unroll
        for (int ct = 0; ct < 8; ++ct) {
            int c = ct * 16 + t;
            {
                int ch = g ^ (c & 7);
                bf16x8 vf = *(const bf16x8*)&lV[c * 64 + ch * 8];
                acco[ct] = __builtin_amdgcn_mfma_f32_16x16x32_bf16(vf, pa0.v, acco[ct], 0, 0, 0);
            }
            {
                int ch = (g + 4) ^ (c & 7);
                bf16x8 vf = *(const bf16x8*)&lV[c * 64 + ch * 8];
                acco[ct] = __builtin_amdgcn_mfma_f32_16x16x32_bf16(vf, pa1.v, acco[ct], 0, 0, 0);
            }
        }
        __builtin_amdgcn_s_setprio(0);

        // end-of-iter barrier: drains this iter's prefetch (overlapped
        // with the compute above) and closes reads of buf[cur]
        __syncthreads();
        cur ^= 1;
    }

    // ---- epilogue: out = x * (O / l) ----
    float inv = 1.0f / lsum;
    #pragma unroll
    for (int ct = 0; ct < 8; ++ct) {
        #pragma unroll
        for (int r = 0; r < 4; ++r) {
            int c = ct * 16 + g * 4 + r;
            long gi = (((long)(b * 128 + c)) << 12) + s0 + (wv << 4) + t;
            out[gi] = x[gi] * acco[ct][r] * inv;
        }
    }
}

// ============================================================
extern "C" void kernel_launch(void* const* d_in, const int* in_sizes, int n_in,
                              void* d_out, int out_size, void* d_ws, size_t ws_size,
                              hipStream_t stream)
{
    const float* x    = (const float*)d_in[0];
    const float* gw   = (const float*)d_in[1];
    const float* gb   = (const float*)d_in[2];
    const float* w    = (const float*)d_in[3];
    const float* bias = (const float*)d_in[4];
    float* out = (float*)d_out;

    u16* hn  = (u16*)d_ws;                        // [8][4096][128] bf16 = 8 MB
    u16* Qt  = hn + (size_t)8 * 4096 * 128;       // [8][4096][128] bf16 = 8 MB
    u16* Kt  = Qt + (size_t)8 * 4096 * 128;       // [8][4096][128] bf16 = 8 MB
    u16* Vv  = Kt + (size_t)8 * 4096 * 128;       // [8][128][4096] bf16 = 8 MB
    u16* wbf = Vv + (size_t)8 * 128 * 4096;       // [384][128] bf16 = 96 KB
    float* gp = (float*)(wbf + (size_t)384 * 128); // [8][128]
    float* bp = gp + 1024;                         // [8][128]

    stats_kernel<<<256, 256, 0, stream>>>(x, gw, gb, gp, bp);
    wconv_kernel<<<48, 256, 0, stream>>>(w, wbf);
    apply_kernel<<<256, 256, 0, stream>>>(x, gp, bp, hn);
    qkvm_kernel<<<512, 256, 0, stream>>>(hn, wbf, bias, Qt, Kt, Vv);
    attn_kernel<<<512, 256, 0, stream>>>(Qt, Kt, Vv, x, out);
}